// Round 1
// baseline (298.551 us; speedup 1.0000x reference)
//
#include <hip/hip_runtime.h>
#include <math.h>

#define WH     256
#define NDEPTH 8
#define NBATCH 1024
#define NB     8          // batch elements per block (register-resident reuse)
#define PLANE  (WH * WH)  // 65536

// ---------------------------------------------------------------------------
// Transpose [d][w][h] -> [d][h][w] so the main kernel's lanes (which own w)
// load coalesced. Classic 32x32 LDS tile with +1 pad.
// grid = (8 h-tiles, 8 w-tiles, 8 depths), block = (32, 8)
// ---------------------------------------------------------------------------
__global__ __launch_bounds__(256) void transpose_k(const float* __restrict__ src,
                                                   float* __restrict__ dst) {
    __shared__ float tile[32][33];
    const int d  = blockIdx.z;
    const int ht = blockIdx.x;
    const int wt = blockIdx.y;
    const int tx = threadIdx.x;   // 0..31
    const int ty = threadIdx.y;   // 0..7
    const float* s = src + d * PLANE;
    float*       o = dst + d * PLANE;

    const int h = ht * 32 + tx;   // coalesced read along h
#pragma unroll
    for (int j = 0; j < 32; j += 8) {
        const int w = wt * 32 + ty + j;
        tile[ty + j][tx] = s[w * WH + h];
    }
    __syncthreads();
    const int w2 = wt * 32 + tx;  // coalesced write along w
#pragma unroll
    for (int j = 0; j < 32; j += 8) {
        const int h2 = ht * 32 + ty + j;
        o[h2 * WH + w2] = tile[tx][ty + j];
    }
}

// ---------------------------------------------------------------------------
// Main kernel. grid = (128 batch-groups, 2 branches), block = 256 threads.
// Thread t owns w = t and NB=8 batch elements in registers.
// TR=1: data is transposed [d][h][w] (fast path, coalesced).
// TR=0: original [d][w][h] (fallback if workspace too small).
// ---------------------------------------------------------------------------
template <int TR>
__global__ __launch_bounds__(256) void prop_k(const float* __restrict__ M1,
                                              const float* __restrict__ B1,
                                              const float* __restrict__ M2,
                                              const float* __restrict__ B2,
                                              const float* __restrict__ val,
                                              float* __restrict__ out) {
    const int br   = blockIdx.y;
    const int bg   = blockIdx.x;          // batch group (8 batches)
    const int w    = threadIdx.x;         // 0..255, owns column w
    const int lane = w & 63;
    const int wave = w >> 6;

    const float* __restrict__ M = br ? M2 : M1;
    const float* __restrict__ B = br ? B2 : B1;

    float q[NB];
#pragma unroll
    for (int nb = 0; nb < NB; ++nb) q[nb] = val[bg * NB + nb];  // uniform -> s_load

    __shared__ float part[4][NB];

    for (int d = 0; d < NDEPTH; ++d) {
        const float* __restrict__ Md = M + d * PLANE;
        const float* __restrict__ Bd = B + d * PLANE;

        float acc[NB];
#pragma unroll
        for (int nb = 0; nb < NB; ++nb) acc[nb] = -INFINITY;

#pragma unroll 2
        for (int h = 0; h < WH; h += 4) {
            // idx: TR -> [h][w] (lanes coalesced), else [w][h]
            const int i0 = TR ? ((h + 0) * WH + w) : (w * WH + h + 0);
            const int i1 = TR ? ((h + 1) * WH + w) : (w * WH + h + 1);
            const int i2 = TR ? ((h + 2) * WH + w) : (w * WH + h + 2);
            const int i3 = TR ? ((h + 3) * WH + w) : (w * WH + h + 3);
            const float m0 = Md[i0], b0 = Bd[i0];
            const float m1 = Md[i1], b1 = Bd[i1];
            const float m2 = Md[i2], b2 = Bd[i2];
            const float m3 = Md[i3], b3 = Bd[i3];
#pragma unroll
            for (int nb = 0; nb < NB; ++nb) {
                const float s0 = fmaf(q[nb], m0, b0);
                const float s1 = fmaf(q[nb], m1, b1);
                const float s2 = fmaf(q[nb], m2, b2);
                const float s3 = fmaf(q[nb], m3, b3);
                // fmax(fmax(a,b),c) folds to v_max3_f32
                acc[nb] = fmaxf(acc[nb], fmaxf(s0, s1));
                acc[nb] = fmaxf(acc[nb], fmaxf(s2, s3));
            }
        }

        // min over all 256 w: 64-lane butterfly, then combine 4 waves via LDS
#pragma unroll
        for (int nb = 0; nb < NB; ++nb) {
            float v = acc[nb];
#pragma unroll
            for (int off = 32; off > 0; off >>= 1)
                v = fminf(v, __shfl_xor(v, off, 64));
            if (lane == 0) part[wave][nb] = v;
        }
        __syncthreads();
#pragma unroll
        for (int nb = 0; nb < NB; ++nb)
            q[nb] = fminf(fminf(part[0][nb], part[1][nb]),
                          fminf(part[2][nb], part[3][nb]));
        __syncthreads();  // part[] reused next depth
    }

    if (w < NB) out[br * NBATCH + bg * NB + w] = q[w];
}

// ---------------------------------------------------------------------------
extern "C" void kernel_launch(void* const* d_in, const int* in_sizes, int n_in,
                              void* d_out, int out_size, void* d_ws, size_t ws_size,
                              hipStream_t stream) {
    const float* val = (const float*)d_in[0];
    const float* M1  = (const float*)d_in[1];
    const float* B1  = (const float*)d_in[2];
    const float* M2  = (const float*)d_in[3];
    const float* B2  = (const float*)d_in[4];
    float* out = (float*)d_out;

    const size_t arr_elems = (size_t)NDEPTH * PLANE;          // 524288 floats
    const size_t need      = 4 * arr_elems * sizeof(float);   // 8 MiB

    if (ws_size >= need) {
        float* ws  = (float*)d_ws;
        float* MT1 = ws + 0 * arr_elems;
        float* BT1 = ws + 1 * arr_elems;
        float* MT2 = ws + 2 * arr_elems;
        float* BT2 = ws + 3 * arr_elems;

        dim3 tg(8, 8, NDEPTH), tb(32, 8);
        transpose_k<<<tg, tb, 0, stream>>>(M1, MT1);
        transpose_k<<<tg, tb, 0, stream>>>(B1, BT1);
        transpose_k<<<tg, tb, 0, stream>>>(M2, MT2);
        transpose_k<<<tg, tb, 0, stream>>>(B2, BT2);

        prop_k<1><<<dim3(NBATCH / NB, 2), 256, 0, stream>>>(MT1, BT1, MT2, BT2, val, out);
    } else {
        // workspace too small for transposed copies: strided-but-correct path
        prop_k<0><<<dim3(NBATCH / NB, 2), 256, 0, stream>>>(M1, B1, M2, B2, val, out);
    }
}

// Round 2
// 150.119 us; speedup vs baseline: 1.9888x; 1.9888x over previous
//
#include <hip/hip_runtime.h>
#include <math.h>

#define WH     256
#define NDEPTH 8
#define NBATCH 1024
#define NB     8          // batch elements per block (register-resident reuse)
#define PLANE  (WH * WH)  // 65536

// ---------------------------------------------------------------------------
// Fused transpose: all 4 arrays, [d][w][h] -> [d][h][w].
// grid = (8 h-tiles, 8 w-tiles, 32 = arr*8+d), block = (32, 8)
// ---------------------------------------------------------------------------
__global__ __launch_bounds__(256) void transpose_all_k(const float* __restrict__ M1,
                                                       const float* __restrict__ B1,
                                                       const float* __restrict__ M2,
                                                       const float* __restrict__ B2,
                                                       float* __restrict__ ws) {
    __shared__ float tile[32][33];
    const int z   = blockIdx.z;
    const int arr = z >> 3;       // 0..3 selects M1,B1,M2,B2 (block-uniform)
    const int d   = z & 7;
    const int ht  = blockIdx.x;
    const int wt  = blockIdx.y;
    const int tx  = threadIdx.x;  // 0..31
    const int ty  = threadIdx.y;  // 0..7

    const float* src = (arr == 0) ? M1 : (arr == 1) ? B1 : (arr == 2) ? M2 : B2;
    const float* s = src + d * PLANE;
    float*       o = ws + (size_t)arr * NDEPTH * PLANE + d * PLANE;

    const int h = ht * 32 + tx;   // coalesced read along h
#pragma unroll
    for (int j = 0; j < 32; j += 8) {
        const int w = wt * 32 + ty + j;
        tile[ty + j][tx] = s[w * WH + h];
    }
    __syncthreads();
    const int w2 = wt * 32 + tx;  // coalesced write along w
#pragma unroll
    for (int j = 0; j < 32; j += 8) {
        const int h2 = ht * 32 + ty + j;
        o[h2 * WH + w2] = tile[tx][ty + j];
    }
}

// ---------------------------------------------------------------------------
// Main kernel. 1D grid of 256 blocks, 256 threads (4 waves).
// Decode: xcd-pinned swizzle — br = (bid%8)>=4, so each branch's 4 MiB
// working set maps to 4 XCDs' L2.
// Wave ws owns h in [ws*64, ws*64+64); lane owns w = lane*4 .. lane*4+3
// via float4 loads from the transposed [d][h][w] layout.
// Per depth: thread-local max over h-chunk, LDS combine (max across waves,
// min over w), broadcast new q.
// ---------------------------------------------------------------------------
__global__ __launch_bounds__(256) void prop_k(const float4* __restrict__ MT1,
                                              const float4* __restrict__ BT1,
                                              const float4* __restrict__ MT2,
                                              const float4* __restrict__ BT2,
                                              const float* __restrict__ val,
                                              float* __restrict__ out) {
    const int bid  = blockIdx.x;
    const int g    = bid >> 3;            // 0..31
    const int x    = bid & 7;             // xcd hint
    const int br   = x >> 2;              // branch 0 -> xcd 0..3, branch 1 -> 4..7
    const int bg   = g * 4 + (x & 3);     // 0..127 batch group
    const int t    = threadIdx.x;
    const int wave = t >> 6;              // 0..3: h-chunk
    const int lane = t & 63;              // owns w4 = lane*4

    const float4* __restrict__ M = br ? MT2 : MT1;
    const float4* __restrict__ B = br ? BT2 : BT1;

    float q[NB];
#pragma unroll
    for (int nb = 0; nb < NB; ++nb) q[nb] = val[bg * NB + nb];  // uniform

    __shared__ float lds[4][NB][WH];   // 32 KiB: [wave][nb][w]
    __shared__ float qs[NB];

    for (int d = 0; d < NDEPTH; ++d) {
        // float4 plane base: PLANE/4 float4s per depth; row h has 64 float4s
        const float4* __restrict__ Md = M + d * (PLANE / 4) + wave * 64 * 64 + lane;
        const float4* __restrict__ Bd = B + d * (PLANE / 4) + wave * 64 * 64 + lane;

        float acc[NB][4];
#pragma unroll
        for (int nb = 0; nb < NB; ++nb)
#pragma unroll
            for (int c = 0; c < 4; ++c) acc[nb][c] = -INFINITY;

        // double-buffered pipeline over 16 chunks of 4 h
        float4 m[2][4], b[2][4];
#pragma unroll
        for (int u = 0; u < 4; ++u) {
            m[0][u] = Md[u * 64];
            b[0][u] = Bd[u * 64];
        }
#pragma unroll 4
        for (int ch = 0; ch < 16; ++ch) {
            const int cur = ch & 1, nxt = cur ^ 1;
            if (ch < 15) {
                const int hb = (ch + 1) * 4;
#pragma unroll
                for (int u = 0; u < 4; ++u) {
                    m[nxt][u] = Md[(hb + u) * 64];
                    b[nxt][u] = Bd[(hb + u) * 64];
                }
            }
#pragma unroll
            for (int u = 0; u < 4; ++u) {
#pragma unroll
                for (int nb = 0; nb < NB; ++nb) {
                    acc[nb][0] = fmaxf(acc[nb][0], fmaf(q[nb], m[cur][u].x, b[cur][u].x));
                    acc[nb][1] = fmaxf(acc[nb][1], fmaf(q[nb], m[cur][u].y, b[cur][u].y));
                    acc[nb][2] = fmaxf(acc[nb][2], fmaf(q[nb], m[cur][u].z, b[cur][u].z));
                    acc[nb][3] = fmaxf(acc[nb][3], fmaf(q[nb], m[cur][u].w, b[cur][u].w));
                }
            }
        }

        // stage per-wave partial maxes: lds[wave][nb][lane*4 + c]
#pragma unroll
        for (int nb = 0; nb < NB; ++nb) {
            float4 v = make_float4(acc[nb][0], acc[nb][1], acc[nb][2], acc[nb][3]);
            *(float4*)&lds[wave][nb][lane * 4] = v;
        }
        __syncthreads();

        // reduce: thread t handles nb = t>>5, w = (t&31) + 32k
        {
            const int nb = t >> 5;
            const int wq = t & 31;
            float v = INFINITY;
#pragma unroll
            for (int k = 0; k < 8; ++k) {
                const int w = wq + 32 * k;
                const float s01 = fmaxf(lds[0][nb][w], lds[1][nb][w]);
                const float s23 = fmaxf(lds[2][nb][w], lds[3][nb][w]);
                v = fminf(v, fmaxf(s01, s23));
            }
#pragma unroll
            for (int off = 16; off > 0; off >>= 1)
                v = fminf(v, __shfl_xor(v, off, 64));   // stays within 32-lane half
            if (wq == 0) qs[nb] = v;
        }
        __syncthreads();
#pragma unroll
        for (int nb = 0; nb < NB; ++nb) q[nb] = qs[nb];
        // lds reads all happened before the sync above; next depth's writes are
        // ordered after it for every thread, so no extra barrier needed.
    }

    if (t < NB) out[br * NBATCH + bg * NB + t] = qs[t];
}

// ---------------------------------------------------------------------------
extern "C" void kernel_launch(void* const* d_in, const int* in_sizes, int n_in,
                              void* d_out, int out_size, void* d_ws, size_t ws_size,
                              hipStream_t stream) {
    const float* val = (const float*)d_in[0];
    const float* M1  = (const float*)d_in[1];
    const float* B1  = (const float*)d_in[2];
    const float* M2  = (const float*)d_in[3];
    const float* B2  = (const float*)d_in[4];
    float* out = (float*)d_out;

    const size_t arr_elems = (size_t)NDEPTH * PLANE;  // 524288 floats per array
    float* ws  = (float*)d_ws;
    float* MT1 = ws + 0 * arr_elems;
    float* BT1 = ws + 1 * arr_elems;
    float* MT2 = ws + 2 * arr_elems;
    float* BT2 = ws + 3 * arr_elems;

    transpose_all_k<<<dim3(8, 8, 32), dim3(32, 8), 0, stream>>>(M1, B1, M2, B2, ws);

    prop_k<<<dim3(256), 256, 0, stream>>>((const float4*)MT1, (const float4*)BT1,
                                          (const float4*)MT2, (const float4*)BT2,
                                          val, out);
}